// Round 6
// baseline (527.474 us; speedup 1.0000x reference)
//
#include <hip/hip_runtime.h>

#define Bn 64
#define Nn 1024
#define Cc 128

typedef _Float16 h8 __attribute__((ext_vector_type(8)));
typedef __fp16 fp16x2 __attribute__((ext_vector_type(2)));
typedef float f4v __attribute__((ext_vector_type(4)));
typedef unsigned long long u64;

// ---------------- featurize + adjacency pack ----------------
// x0 = nf @ W_in (fp16 grouped layout): element (n,c) at ((n>>3)*128 + c)*8 + (n&7)
// E=exp(ai), G=exp(0.2 ai), F=exp(aj), H=exp(0.2 aj)
// alpha = mask * max(E_i*F_j, G_i*H_j) since exp(leakyrelu(e)) = max(exp(e), exp(0.2e))
// Also packs adjacency rows into bitmask pm (row-major 128 B/row).
__global__ __launch_bounds__(256) void k_feat(
    const float* __restrict__ nf, const float* __restrict__ Win,
    const float* __restrict__ asrc, const float* __restrict__ adst,
    const int* __restrict__ adj, _Float16* __restrict__ X0, u64* __restrict__ pm,
    float* __restrict__ E, float* __restrict__ G, float* __restrict__ F, float* __restrict__ H) {
  int g = blockIdx.x; int b = g >> 7; int n0 = (g & 127) << 3;
  int t = threadIdx.x; int c = t >> 1; int h = t & 1;
  int lane = t & 63, wv = t >> 6;
  __shared__ float sNf[24];
  if (t < 24) sNf[t] = nf[((size_t)(b << 10) + n0) * 3 + t];
  float w0 = Win[c], w1 = Win[Cc + c], w2 = Win[2 * Cc + c];
  float as_ = asrc[c], ad = adst[c];
  __syncthreads();
  float ps[4], pd[4];
  _Float16 hv[4];
  #pragma unroll
  for (int r = 0; r < 4; r++) {
    const float* p = sNf + ((h << 2) + r) * 3;
    float x = p[0] * w0 + p[1] * w1 + p[2] * w2;
    hv[r] = (_Float16)x; ps[r] = x * as_; pd[r] = x * ad;
  }
  *(uint2*)(X0 + ((size_t)b << 17) + ((size_t)(g & 127) << 10) + (c << 3) + (h << 2)) = *(uint2*)hv;

  // ---- adjacency bit-pack: wave wv packs rows n0+2*wv, n0+2*wv+1 of batch b ----
  {
    ushort* pmu = (ushort*)pm;
    int row = n0 + (wv << 1);
    const uint4* ar = (const uint4*)(adj + (((size_t)(b << 10) + row) << 10));
    #pragma unroll
    for (int rr = 0; rr < 2; rr++) {
      uint4 v0 = ar[(lane << 2) | 0], v1 = ar[(lane << 2) | 1];
      uint4 v2 = ar[(lane << 2) | 2], v3 = ar[(lane << 2) | 3];
      unsigned int bits =
          (v0.x) | (v0.y << 1) | (v0.z << 2) | (v0.w << 3) |
          (v1.x << 4) | (v1.y << 5) | (v1.z << 6) | (v1.w << 7) |
          (v2.x << 8) | (v2.y << 9) | (v2.z << 10) | (v2.w << 11) |
          (v3.x << 12) | (v3.y << 13) | (v3.z << 14) | (v3.w << 15);
      pmu[(((size_t)(b << 10) + row + rr) << 6) + lane] = (ushort)bits;
      ar += 256;  // next row (1024 ints)
    }
  }

  #pragma unroll
  for (int off = 32; off > 1; off >>= 1) {
    #pragma unroll
    for (int r = 0; r < 4; r++) { ps[r] += __shfl_down(ps[r], off, 64); pd[r] += __shfl_down(pd[r], off, 64); }
  }
  __shared__ float red[4][2][4][2];
  if (lane < 2) {
    #pragma unroll
    for (int r = 0; r < 4; r++) { red[wv][lane][r][0] = ps[r]; red[wv][lane][r][1] = pd[r]; }
  }
  __syncthreads();
  if (t < 8) {
    int hh = t >> 2, r = t & 3;
    float sa = 0.f, sd = 0.f;
    #pragma unroll
    for (int w = 0; w < 4; w++) { sa += red[w][hh][r][0]; sd += red[w][hh][r][1]; }
    int gi = (b << 10) + n0 + t;
    E[gi] = __expf(sa); G[gi] = __expf(0.2f * sa);
    F[gi] = __expf(sd); H[gi] = __expf(0.2f * sd);
  }
}

// ------- MFMA aggregation: 32-row tiles for 100% occupancy -------
// out[i,c] = relu( (1/den_i) * sum_j alpha_ij * x[j,c] ),  den_i = sum_j alpha_ij
// alpha_ij = mask_ij * max(E_i*F_j, G_i*H_j)
// Grid 2048 blocks (32 tiles x 64 batches) -> 8 blocks/CU x 4 waves = 32 waves/CU
// (round-2 profile showed latency-bound at 50% occupancy: MfmaUtil 4%, VALUBusy 23%).
// Wave (wi,wc): rows wi*16..+16, cols wc*64..+64 -> 1 A-frag, 4 B-frags, 5 MFMA/kt.
// B straight from global (grouped layout == fragment layout, XCD-pinned: lin&63=batch).
// den via accD = mfma(A, ones): reg r of lane (m,quad) = den[row quad*4+r] (exact C rows).
template <int LAYER>
__global__ __launch_bounds__(256, 8) void k_agg(
    const _Float16* __restrict__ X,
    const float* __restrict__ E, const float* __restrict__ G,
    const float* __restrict__ F, const float* __restrict__ H,
    const u64* __restrict__ pm, _Float16* __restrict__ Y, float* __restrict__ xmp,
    const float* __restrict__ as2, const float* __restrict__ ad2,
    float* __restrict__ E2o, float* __restrict__ G2o,
    float* __restrict__ F2o, float* __restrict__ H2o) {
  __shared__ __align__(16) char smem[17920];
  float* s_F  = (float*)smem;                            // 4 KB
  float* s_H  = (float*)(smem + 4096);                   // 4 KB
  unsigned char* s_pm = (unsigned char*)(smem + 8192);   // 32 rows x 152 B = 4864 B
  float* tile = (float*)smem;                            // epilogue overlay [32][132] = 16896 B
  float* s_as2 = (float*)(smem + 16896);                 // 512 B (LAYER 1 only)
  float* s_ad2 = (float*)(smem + 17408);                 // 512 B

  // XCD-locality swizzle: batch = lin & 63 -> batch b's 32 tiles on XCD (b % 8)
  const int lin = blockIdx.x;
  const int b = lin & 63, tile_id = lin >> 6, i0 = tile_id << 5;
  const int tid = threadIdx.x;
  const int lane = tid & 63, wv = tid >> 6;
  const int m = lane & 15, quad = lane >> 4;
  const int wi = wv >> 1, wc = wv & 1;
  const int gbase = b << 10;

  // stage col-side arrays (F, H) and packed mask (32 rows x 16 u64)
  ((float4*)s_F)[tid] = ((const float4*)(F + gbase))[tid];
  ((float4*)s_H)[tid] = ((const float4*)(H + gbase))[tid];
  {
    const u64* pmg = pm + ((size_t)(gbase + i0) << 4);
    #pragma unroll
    for (int k = tid; k < 512; k += 256) {
      int r = k >> 4, w = k & 15;
      *(u64*)(s_pm + r * 152 + (w << 3)) = pmg[k];
    }
  }
  if (LAYER == 1 && tid < 128) { s_as2[tid] = as2[tid]; s_ad2[tid] = ad2[tid]; }

  // per-lane row constants: this lane owns output rows r0 = wi*16 + m
  const int r0 = (wi << 4) + m;
  const int gi0 = gbase + i0 + r0;
  const float E0c = E[gi0], G0c = G[gi0];

  f4v acc[4];
  #pragma unroll
  for (int ct = 0; ct < 4; ct++) { f4v z = {0.f, 0.f, 0.f, 0.f}; acc[ct] = z; }
  f4v accD = {0.f, 0.f, 0.f, 0.f};
  const h8 kOne = {(_Float16)1.f, (_Float16)1.f, (_Float16)1.f, (_Float16)1.f,
                   (_Float16)1.f, (_Float16)1.f, (_Float16)1.f, (_Float16)1.f};

  // B fragment base: grouped layout => global byte offset == fragment byte offset
  const char* gB = (const char*)(X + ((size_t)b << 17)) + (((quad << 7) + (wc << 6) + m) << 4);
  const unsigned char* pmr0 = s_pm + r0 * 152;

  __syncthreads();  // staging visible to all waves

  // bit-mask byte -> 4 u32 AND-masks (fp16x2 lanes)
  auto expand = [](unsigned mb, unsigned M[4]) {
    unsigned slo = ((mb & 0xFu) * 0x204081u) & 0x01010101u;
    unsigned shi = (((mb >> 4) & 0xFu) * 0x204081u) & 0x01010101u;
    slo *= 0xFFu; shi *= 0xFFu;
    M[0] = __builtin_amdgcn_perm(slo, slo, 0x01010000u);
    M[1] = __builtin_amdgcn_perm(slo, slo, 0x03030202u);
    M[2] = __builtin_amdgcn_perm(shi, shi, 0x01010000u);
    M[3] = __builtin_amdgcn_perm(shi, shi, 0x03030202u);
  };

  auto LOADB = [&](int kt, h8* Bf, unsigned& mb0) {
    const char* gp = gB + ((size_t)kt << 13);
    Bf[0] = *(const h8*)gp;          Bf[1] = *(const h8*)(gp + 256);
    Bf[2] = *(const h8*)(gp + 512);  Bf[3] = *(const h8*)(gp + 768);
    mb0 = pmr0[(kt << 2) + quad];
  };
  auto COMP = [&](int kt, const h8* Bf, unsigned mb0) {
    const int j0 = (kt << 5) + (quad << 3);
    float f[8], hh[8];
    *(float4*)&f[0]  = *(const float4*)&s_F[j0]; *(float4*)&f[4]  = *(const float4*)&s_F[j0 + 4];
    *(float4*)&hh[0] = *(const float4*)&s_H[j0]; *(float4*)&hh[4] = *(const float4*)&s_H[j0 + 4];
    unsigned M0[4];
    expand(mb0, M0);
    union { h8 v; unsigned u[4]; } A0;
    #pragma unroll
    for (int q = 0; q < 4; q++) {
      float u0 = fmaxf(E0c * f[2 * q], G0c * hh[2 * q]);
      float u1 = fmaxf(E0c * f[2 * q + 1], G0c * hh[2 * q + 1]);
      fp16x2 p0 = __builtin_amdgcn_cvt_pkrtz(u0, u1);
      unsigned p0u; __builtin_memcpy(&p0u, &p0, 4);
      A0.u[q] = p0u & M0[q];
    }
    acc[0] = __builtin_amdgcn_mfma_f32_16x16x32_f16(A0.v, Bf[0], acc[0], 0, 0, 0);
    acc[1] = __builtin_amdgcn_mfma_f32_16x16x32_f16(A0.v, Bf[1], acc[1], 0, 0, 0);
    acc[2] = __builtin_amdgcn_mfma_f32_16x16x32_f16(A0.v, Bf[2], acc[2], 0, 0, 0);
    acc[3] = __builtin_amdgcn_mfma_f32_16x16x32_f16(A0.v, Bf[3], acc[3], 0, 0, 0);
    accD   = __builtin_amdgcn_mfma_f32_16x16x32_f16(A0.v, kOne, accD, 0, 0, 0);
  };

  // 1-deep software pipeline on the global B fragments + mask byte
  h8 Bf0[4], Bf1[4]; unsigned m00, m10;
  LOADB(0, Bf0, m00);
  for (int kt = 0; kt < 32; kt += 2) {
    LOADB(kt + 1, Bf1, m10);
    COMP(kt, Bf0, m00);
    LOADB(kt + 2, Bf0, m00);  // kt=30 -> 32: benign prefetch (valid ws memory / in-row pm bytes)
    COMP(kt + 1, Bf1, m10);
  }

  // per-lane reciprocal denominators: reg r of accD = den[row (wi*16 + quad*4 + r)]
  float rd[4];
  #pragma unroll
  for (int r = 0; r < 4; r++) rd[r] = 1.0f / accD[r];

  __syncthreads();  // all waves done reading s_F/s_H/s_pm before tile overlay
  // write relu(acc/den) into fp32 tile [32][132]
  #pragma unroll
  for (int ct = 0; ct < 4; ct++)
    #pragma unroll
    for (int r = 0; r < 4; r++) {
      int lr = (wi << 4) + (quad << 2) + r;
      int c = (wc << 6) + (ct << 4) + m;
      tile[lr * 132 + c] = fmaxf(acc[ct][r] * rd[r], 0.f);
    }
  __syncthreads();
  if (LAYER == 1) {
    // coalesced fp16 grouped-layout store: block region is contiguous [i0*128, +4096)
    _Float16 hv[16];
    #pragma unroll
    for (int s = 0; s < 16; s++) {
      int q = (tid << 4) + s;
      int li = ((q >> 10) << 3) + (q & 7), c = (q >> 3) & 127;
      hv[s] = (_Float16)tile[li * 132 + c];
    }
    uint4* o = (uint4*)(Y + ((size_t)b << 17) + ((size_t)i0 << 7) + (tid << 4));
    o[0] = *(uint4*)&hv[0]; o[1] = *(uint4*)&hv[8];
    // fused layer-2 scores: 8 threads/row, 16 cols each, xor-reduce over 8 lanes
    {
      int i = tid >> 3, p = tid & 7, cb = p << 4;
      const float* trow = tile + i * 132 + cb;
      float ssrc = 0.f, sdst = 0.f;
      #pragma unroll
      for (int k = 0; k < 16; k += 4) {
        float4 tv = *(const float4*)(trow + k);
        float4 av = *(const float4*)(s_as2 + cb + k);
        float4 dv = *(const float4*)(s_ad2 + cb + k);
        ssrc += tv.x * av.x + tv.y * av.y + tv.z * av.z + tv.w * av.w;
        sdst += tv.x * dv.x + tv.y * dv.y + tv.z * dv.z + tv.w * dv.w;
      }
      ssrc += __shfl_xor(ssrc, 1, 64); ssrc += __shfl_xor(ssrc, 2, 64); ssrc += __shfl_xor(ssrc, 4, 64);
      sdst += __shfl_xor(sdst, 1, 64); sdst += __shfl_xor(sdst, 2, 64); sdst += __shfl_xor(sdst, 4, 64);
      int gi = gbase + i0 + i;
      if (p == 0) { E2o[gi] = __expf(ssrc); G2o[gi] = __expf(0.2f * ssrc); }
      else if (p == 1) { F2o[gi] = __expf(sdst); H2o[gi] = __expf(0.2f * sdst); }
    }
  } else {
    // node-mean partial: column sums -> per-(block,batch) partial slot (deterministic)
    if (tid < 128) {
      float s = 0.f;
      #pragma unroll
      for (int i = 0; i < 32; i++) s += tile[i * 132 + tid];
      xmp[(((b << 5) + tile_id) << 7) + tid] = s;
    }
  }
}

// ---------------- fused MLP head (sums the 32 mean-partials) ----------------
__global__ __launch_bounds__(256) void k_head(
    const float* __restrict__ xmp, const float* __restrict__ W1, const float* __restrict__ b1,
    const float* __restrict__ W2, const float* __restrict__ b2,
    const float* __restrict__ Wpi, const float* __restrict__ bpi,
    const float* __restrict__ Wv, const float* __restrict__ bv,
    float* __restrict__ out) {
  int b = blockIdx.x, t = threadIdx.x;
  __shared__ float xs[128], h1[256], h2[128], red[4];
  if (t < 128) {
    const float* p = xmp + ((size_t)b << 12);
    float s = 0.f;
    #pragma unroll
    for (int xb = 0; xb < 32; xb++) s += p[(xb << 7) + t];
    xs[t] = s * (1.f / 1024.f);
  }
  __syncthreads();
  float s = 0.f;
  #pragma unroll 8
  for (int k = 0; k < 128; k++) s += xs[k] * W1[k * 256 + t];
  h1[t] = fmaxf(s + b1[t], 0.f);
  __syncthreads();
  if (t < 128) {
    float s2 = 0.f;
    #pragma unroll 8
    for (int k = 0; k < 256; k++) s2 += h1[k] * W2[k * 128 + t];
    h2[t] = fmaxf(s2 + b2[t], 0.f);
  }
  __syncthreads();
  float lg[4];
  #pragma unroll
  for (int q = 0; q < 4; q++) {
    int o = t + (q << 8);
    float s3 = 0.f;
    #pragma unroll 8
    for (int k = 0; k < 128; k++) s3 += h2[k] * Wpi[k * 1024 + o];
    lg[q] = s3 + bpi[o];
  }
  float mx = fmaxf(fmaxf(lg[0], lg[1]), fmaxf(lg[2], lg[3]));
  #pragma unroll
  for (int off = 32; off > 0; off >>= 1) mx = fmaxf(mx, __shfl_down(mx, off, 64));
  if ((t & 63) == 0) red[t >> 6] = mx;
  __syncthreads();
  mx = fmaxf(fmaxf(red[0], red[1]), fmaxf(red[2], red[3]));
  __syncthreads();
  float ex[4]; float sum = 0.f;
  #pragma unroll
  for (int q = 0; q < 4; q++) { ex[q] = __expf(lg[q] - mx); sum += ex[q]; }
  #pragma unroll
  for (int off = 32; off > 0; off >>= 1) sum += __shfl_down(sum, off, 64);
  if ((t & 63) == 0) red[t >> 6] = sum;
  __syncthreads();
  sum = red[0] + red[1] + red[2] + red[3];
  float rs = 1.0f / sum;
  #pragma unroll
  for (int q = 0; q < 4; q++) out[((size_t)b << 10) + t + (q << 8)] = ex[q] * rs;
  __syncthreads();
  float vp = (t < 128) ? h2[t] * Wv[t] : 0.f;
  #pragma unroll
  for (int off = 32; off > 0; off >>= 1) vp += __shfl_down(vp, off, 64);
  if ((t & 63) == 0) red[t >> 6] = vp;
  __syncthreads();
  if (t == 0) out[65536 + b] = red[0] + red[1] + red[2] + red[3] + bv[0];
}

extern "C" void kernel_launch(void* const* d_in, const int* in_sizes, int n_in,
                              void* d_out, int out_size, void* d_ws, size_t ws_size,
                              hipStream_t stream) {
  const float* nf    = (const float*)d_in[0];
  const int*   adj   = (const int*)  d_in[1];
  const float* Win   = (const float*)d_in[2];
  const float* asrc  = (const float*)d_in[3];
  const float* adst  = (const float*)d_in[4];
  const float* asrc2 = (const float*)d_in[5];
  const float* adst2 = (const float*)d_in[6];
  const float* W1    = (const float*)d_in[7];
  const float* b1    = (const float*)d_in[8];
  const float* W2    = (const float*)d_in[9];
  const float* b2    = (const float*)d_in[10];
  const float* Wpi   = (const float*)d_in[11];
  const float* bpi   = (const float*)d_in[12];
  const float* Wv    = (const float*)d_in[13];
  const float* bv    = (const float*)d_in[14];
  float* out = (float*)d_out;

  char* ws = (char*)d_ws;
  _Float16* x0 = (_Float16*)(ws);                                // 16.78 MB
  _Float16* x1 = (_Float16*)(ws + 16777216);                     // 16.78 MB
  u64* pm = (u64*)(ws + 33554432);                               // 8.39 MB
  char* S = ws + 41943040;
  float* E1  = (float*)(S + 2 * 262144);
  float* G1  = (float*)(S + 3 * 262144);
  float* F1  = (float*)(S + 4 * 262144);
  float* H1  = (float*)(S + 5 * 262144);
  float* E2  = (float*)(S + 8 * 262144);
  float* G2  = (float*)(S + 9 * 262144);
  float* F2  = (float*)(S + 10 * 262144);
  float* H2  = (float*)(S + 11 * 262144);
  float* xmp = (float*)(S + 12 * 262144);                        // 1 MB partials (64x32x128 f32)

  k_feat<<<8192, 256, 0, stream>>>(nf, Win, asrc, adst, adj, x0, pm, E1, G1, F1, H1);
  k_agg<1><<<2048, 256, 0, stream>>>(x0, E1, G1, F1, H1, pm, x1, nullptr,
                                     asrc2, adst2, E2, G2, F2, H2);
  k_agg<2><<<2048, 256, 0, stream>>>(x1, E2, G2, F2, H2, pm, nullptr, xmp,
                                     nullptr, nullptr, nullptr, nullptr, nullptr, nullptr);
  k_head<<<Bn, 256, 0, stream>>>(xmp, W1, b1, W2, b2, Wpi, bpi, Wv, bv, out);
}

// Round 8
// 500.819 us; speedup vs baseline: 1.0532x; 1.0532x over previous
//
#include <hip/hip_runtime.h>

#define Bn 64
#define Nn 1024
#define Cc 128

typedef _Float16 h8 __attribute__((ext_vector_type(8)));
typedef _Float16 h2v __attribute__((ext_vector_type(2)));
typedef float f4v __attribute__((ext_vector_type(4)));
typedef unsigned long long u64;

// ---------------- featurize + adjacency pack ----------------
// x0 = nf @ W_in (fp16 grouped layout): element (n,c) at ((n>>3)*128 + c)*8 + (n&7)
// E=exp(ai), G=exp(0.2 ai) fp32 (row side); Fh=exp(aj), Hh=exp(0.2 aj) fp16 (col side,
// consumed as packed fp16 pairs in the agg K-loop).
// alpha = mask * max(E_i*F_j, G_i*H_j) since exp(leakyrelu(e)) = max(exp(e), exp(0.2e))
// Also packs adjacency rows into bitmask pm (row-major 128 B/row).
__global__ __launch_bounds__(256) void k_feat(
    const float* __restrict__ nf, const float* __restrict__ Win,
    const float* __restrict__ asrc, const float* __restrict__ adst,
    const int* __restrict__ adj, _Float16* __restrict__ X0, u64* __restrict__ pm,
    float* __restrict__ E, float* __restrict__ G,
    _Float16* __restrict__ Fh, _Float16* __restrict__ Hh) {
  int g = blockIdx.x; int b = g >> 7; int n0 = (g & 127) << 3;
  int t = threadIdx.x; int c = t >> 1; int h = t & 1;
  int lane = t & 63, wv = t >> 6;
  __shared__ float sNf[24];
  if (t < 24) sNf[t] = nf[((size_t)(b << 10) + n0) * 3 + t];
  float w0 = Win[c], w1 = Win[Cc + c], w2 = Win[2 * Cc + c];
  float as_ = asrc[c], ad = adst[c];
  __syncthreads();
  float ps[4], pd[4];
  _Float16 hv[4];
  #pragma unroll
  for (int r = 0; r < 4; r++) {
    const float* p = sNf + ((h << 2) + r) * 3;
    float x = p[0] * w0 + p[1] * w1 + p[2] * w2;
    hv[r] = (_Float16)x; ps[r] = x * as_; pd[r] = x * ad;
  }
  *(uint2*)(X0 + ((size_t)b << 17) + ((size_t)(g & 127) << 10) + (c << 3) + (h << 2)) = *(uint2*)hv;

  // ---- adjacency bit-pack: wave wv packs rows n0+2*wv, n0+2*wv+1 of batch b ----
  {
    ushort* pmu = (ushort*)pm;
    int row = n0 + (wv << 1);
    const uint4* ar = (const uint4*)(adj + (((size_t)(b << 10) + row) << 10));
    #pragma unroll
    for (int rr = 0; rr < 2; rr++) {
      uint4 v0 = ar[(lane << 2) | 0], v1 = ar[(lane << 2) | 1];
      uint4 v2 = ar[(lane << 2) | 2], v3 = ar[(lane << 2) | 3];
      unsigned int bits =
          (v0.x) | (v0.y << 1) | (v0.z << 2) | (v0.w << 3) |
          (v1.x << 4) | (v1.y << 5) | (v1.z << 6) | (v1.w << 7) |
          (v2.x << 8) | (v2.y << 9) | (v2.z << 10) | (v2.w << 11) |
          (v3.x << 12) | (v3.y << 13) | (v3.z << 14) | (v3.w << 15);
      pmu[(((size_t)(b << 10) + row + rr) << 6) + lane] = (ushort)bits;
      ar += 256;  // next row (1024 ints)
    }
  }

  #pragma unroll
  for (int off = 32; off > 1; off >>= 1) {
    #pragma unroll
    for (int r = 0; r < 4; r++) { ps[r] += __shfl_down(ps[r], off, 64); pd[r] += __shfl_down(pd[r], off, 64); }
  }
  __shared__ float red[4][2][4][2];
  if (lane < 2) {
    #pragma unroll
    for (int r = 0; r < 4; r++) { red[wv][lane][r][0] = ps[r]; red[wv][lane][r][1] = pd[r]; }
  }
  __syncthreads();
  if (t < 8) {
    int hh = t >> 2, r = t & 3;
    float sa = 0.f, sd = 0.f;
    #pragma unroll
    for (int w = 0; w < 4; w++) { sa += red[w][hh][r][0]; sd += red[w][hh][r][1]; }
    int gi = (b << 10) + n0 + t;
    E[gi] = __expf(sa); G[gi] = __expf(0.2f * sa);
    Fh[gi] = (_Float16)__expf(sd); Hh[gi] = (_Float16)__expf(0.2f * sd);
  }
}

// ------- MFMA aggregation (r4 tiling): 64-row tiles, packed-fp16 alpha gen -------
// out[i,c] = relu( (1/den_i) * sum_j alpha_ij * x[j,c] ),  den_i = sum_j alpha_ij
// alpha_ij = mask_ij * max(E_i*F_j, G_i*H_j)
// K-loop is VALU-bound (r6 occupancy experiment: more waves did NOT help; r2 profile
// MfmaUtil 4%, VALUBusy 23% = issue-limited). This round cuts A-gen VALU ~40%:
// F/H staged as packed fp16 pairs; alpha pair = elementwise_max(E0p*f2, G0p*h2)
// (v_pk_mul_f16 / v_pk_max_f16) + one AND -> 4 packed ops / 2 elements.
// B straight from global (grouped layout == fragment layout, XCD-pinned: lin&63=batch).
// den via accD = mfma(A, ones): reg r of lane (m,quad) = den[row quad*4+r] (exact C rows).
template <int LAYER>
__global__ __launch_bounds__(256, 4) void k_agg(
    const _Float16* __restrict__ X,
    const float* __restrict__ E, const float* __restrict__ G,
    const _Float16* __restrict__ Fh, const _Float16* __restrict__ Hh,
    const u64* __restrict__ pm, _Float16* __restrict__ Y, float* __restrict__ xmp,
    const float* __restrict__ as2, const float* __restrict__ ad2,
    float* __restrict__ E2o, float* __restrict__ G2o,
    _Float16* __restrict__ F2o, _Float16* __restrict__ H2o) {
  __shared__ __align__(16) char smem[34816];
  _Float16* s_Fh = (_Float16*)smem;                      // 2 KB (1024 fp16)
  _Float16* s_Hh = (_Float16*)(smem + 2048);             // 2 KB
  unsigned char* s_pm = (unsigned char*)(smem + 4096);   // 64 rows x 152 B = 9728 B
  float* tile = (float*)smem;                            // epilogue overlay [64][132] = 33792 B
  float* s_as2 = (float*)(smem + 33792);                 // 512 B (LAYER 1 only)
  float* s_ad2 = (float*)(smem + 34304);                 // 512 B

  // XCD-locality swizzle: batch = lin & 63 -> batch b's 16 tiles on XCD (b % 8)
  const int lin = blockIdx.x;
  const int b = lin & 63, tile_id = lin >> 6, i0 = tile_id << 6;
  const int tid = threadIdx.x;
  const int lane = tid & 63, wv = tid >> 6;
  const int m = lane & 15, quad = lane >> 4;
  const int wi = wv >> 1, wc = wv & 1;
  const int gbase = b << 10;

  // stage col-side packed fp16 arrays (Fh, Hh) and packed mask
  ((uint2*)s_Fh)[tid] = ((const uint2*)(Fh + gbase))[tid];
  ((uint2*)s_Hh)[tid] = ((const uint2*)(Hh + gbase))[tid];
  {
    const u64* pmg = pm + ((size_t)(gbase + i0) << 4);
    #pragma unroll
    for (int k = tid; k < 1024; k += 256) {
      int r = k >> 4, w = k & 15;
      *(u64*)(s_pm + r * 152 + (w << 3)) = pmg[k];
    }
  }
  if (LAYER == 1 && tid < 128) { s_as2[tid] = as2[tid]; s_ad2[tid] = ad2[tid]; }

  // per-lane row constants: this lane owns output rows r0 = wi*32+m and r0+16
  const int r0 = (wi << 5) + m;
  const int gi0 = gbase + i0 + r0;
  const _Float16 e0 = (_Float16)E[gi0],      g0 = (_Float16)G[gi0];
  const _Float16 e1 = (_Float16)E[gi0 + 16], g1 = (_Float16)G[gi0 + 16];
  const h2v E0p = {e0, e0}, G0p = {g0, g0}, E1p = {e1, e1}, G1p = {g1, g1};

  f4v acc[2][4];
  #pragma unroll
  for (int a = 0; a < 2; a++)
    #pragma unroll
    for (int ct = 0; ct < 4; ct++) { f4v z = {0.f, 0.f, 0.f, 0.f}; acc[a][ct] = z; }
  f4v accD0 = {0.f, 0.f, 0.f, 0.f}, accD1 = {0.f, 0.f, 0.f, 0.f};
  const h8 kOne = {(_Float16)1.f, (_Float16)1.f, (_Float16)1.f, (_Float16)1.f,
                   (_Float16)1.f, (_Float16)1.f, (_Float16)1.f, (_Float16)1.f};

  // B fragment base: grouped layout => global byte offset == fragment byte offset
  const char* gB = (const char*)(X + ((size_t)b << 17)) + (((quad << 7) + (wc << 6) + m) << 4);
  const unsigned char* pmr0 = s_pm + r0 * 152;
  const unsigned char* pmr1 = pmr0 + 16 * 152;

  __syncthreads();  // staging visible to all waves

  // bit-mask byte -> 4 u32 AND-masks (fp16x2 lanes)
  auto expand = [](unsigned mb, unsigned M[4]) {
    unsigned slo = ((mb & 0xFu) * 0x204081u) & 0x01010101u;
    unsigned shi = (((mb >> 4) & 0xFu) * 0x204081u) & 0x01010101u;
    slo *= 0xFFu; shi *= 0xFFu;
    M[0] = __builtin_amdgcn_perm(slo, slo, 0x01010000u);
    M[1] = __builtin_amdgcn_perm(slo, slo, 0x03030202u);
    M[2] = __builtin_amdgcn_perm(shi, shi, 0x01010000u);
    M[3] = __builtin_amdgcn_perm(shi, shi, 0x03030202u);
  };

  auto LOADB = [&](int kt, h8* Bf, unsigned& mb0, unsigned& mb1) {
    const char* gp = gB + ((size_t)kt << 13);
    Bf[0] = *(const h8*)gp;          Bf[1] = *(const h8*)(gp + 256);
    Bf[2] = *(const h8*)(gp + 512);  Bf[3] = *(const h8*)(gp + 768);
    mb0 = pmr0[(kt << 2) + quad];    mb1 = pmr1[(kt << 2) + quad];
  };
  auto COMP = [&](int kt, const h8* Bf, unsigned mb0, unsigned mb1) {
    const int j0 = (kt << 5) + (quad << 3);
    uint4 Fp = *(const uint4*)((const char*)s_Fh + (j0 << 1));  // 4 packed fp16 pairs
    uint4 Hp = *(const uint4*)((const char*)s_Hh + (j0 << 1));
    unsigned M0[4], M1[4];
    expand(mb0, M0); expand(mb1, M1);
    union { h8 v; unsigned u[4]; } A0, A1;
    const unsigned* fu = (const unsigned*)&Fp;
    const unsigned* hu = (const unsigned*)&Hp;
    #pragma unroll
    for (int q = 0; q < 4; q++) {
      h2v f2, h2;
      __builtin_memcpy(&f2, &fu[q], 4); __builtin_memcpy(&h2, &hu[q], 4);
      h2v mx0 = __builtin_elementwise_max(E0p * f2, G0p * h2);  // v_pk_mul + v_pk_max
      h2v mx1 = __builtin_elementwise_max(E1p * f2, G1p * h2);
      unsigned m0u, m1u;
      __builtin_memcpy(&m0u, &mx0, 4); __builtin_memcpy(&m1u, &mx1, 4);
      A0.u[q] = m0u & M0[q];
      A1.u[q] = m1u & M1[q];
    }
    acc[0][0] = __builtin_amdgcn_mfma_f32_16x16x32_f16(A0.v, Bf[0], acc[0][0], 0, 0, 0);
    acc[1][0] = __builtin_amdgcn_mfma_f32_16x16x32_f16(A1.v, Bf[0], acc[1][0], 0, 0, 0);
    acc[0][1] = __builtin_amdgcn_mfma_f32_16x16x32_f16(A0.v, Bf[1], acc[0][1], 0, 0, 0);
    acc[1][1] = __builtin_amdgcn_mfma_f32_16x16x32_f16(A1.v, Bf[1], acc[1][1], 0, 0, 0);
    acc[0][2] = __builtin_amdgcn_mfma_f32_16x16x32_f16(A0.v, Bf[2], acc[0][2], 0, 0, 0);
    acc[1][2] = __builtin_amdgcn_mfma_f32_16x16x32_f16(A1.v, Bf[2], acc[1][2], 0, 0, 0);
    acc[0][3] = __builtin_amdgcn_mfma_f32_16x16x32_f16(A0.v, Bf[3], acc[0][3], 0, 0, 0);
    acc[1][3] = __builtin_amdgcn_mfma_f32_16x16x32_f16(A1.v, Bf[3], acc[1][3], 0, 0, 0);
    accD0 = __builtin_amdgcn_mfma_f32_16x16x32_f16(A0.v, kOne, accD0, 0, 0, 0);
    accD1 = __builtin_amdgcn_mfma_f32_16x16x32_f16(A1.v, kOne, accD1, 0, 0, 0);
  };

  // 1-deep software pipeline on the global B fragments + mask bytes
  h8 Bf0[4], Bf1[4]; unsigned m00, m01, m10, m11;
  LOADB(0, Bf0, m00, m01);
  for (int kt = 0; kt < 32; kt += 2) {
    LOADB(kt + 1, Bf1, m10, m11);
    COMP(kt, Bf0, m00, m01);
    LOADB(kt + 2, Bf0, m00, m01);  // kt=30 -> 32: benign prefetch (valid ws memory / in-row pm bytes)
    COMP(kt + 1, Bf1, m10, m11);
  }

  // per-lane reciprocal denominators: reg r of accD{a} = den[row (wi*32 + a*16 + quad*4 + r)]
  float rd8[2][4];
  #pragma unroll
  for (int r = 0; r < 4; r++) { rd8[0][r] = 1.0f / accD0[r]; rd8[1][r] = 1.0f / accD1[r]; }

  __syncthreads();  // all waves done reading s_Fh/s_Hh/s_pm before tile overlay
  // write relu(acc/den) into fp32 tile [64][132]
  #pragma unroll
  for (int a = 0; a < 2; a++)
    #pragma unroll
    for (int ct = 0; ct < 4; ct++)
      #pragma unroll
      for (int r = 0; r < 4; r++) {
        int lr = (wi << 5) + (a << 4) + (quad << 2) + r;
        int c = (wc << 6) + (ct << 4) + m;
        tile[lr * 132 + c] = fmaxf(acc[a][ct][r] * rd8[a][r], 0.f);
      }
  __syncthreads();
  if (LAYER == 1) {
    // coalesced fp16 grouped-layout store: block region is contiguous [i0*128, +8192)
    _Float16 hv[32];
    #pragma unroll
    for (int s = 0; s < 32; s++) {
      int q = (tid << 5) + s;
      int li = ((q >> 10) << 3) + (q & 7), c = (q >> 3) & 127;
      hv[s] = (_Float16)tile[li * 132 + c];
    }
    uint4* o = (uint4*)(Y + ((size_t)b << 17) + ((size_t)i0 << 7) + (tid << 5));
    o[0] = *(uint4*)&hv[0]; o[1] = *(uint4*)&hv[8];
    o[2] = *(uint4*)&hv[16]; o[3] = *(uint4*)&hv[24];
    // fused layer-2 scores: row i of this tile, from fp32 values.
    {
      int i = tid >> 2, p = tid & 3, cb = p << 5;
      const float* trow = tile + i * 132 + cb;
      float ssrc = 0.f, sdst = 0.f;
      #pragma unroll
      for (int k = 0; k < 32; k += 4) {
        float4 tv = *(const float4*)(trow + k);
        float4 av = *(const float4*)(s_as2 + cb + k);
        float4 dv = *(const float4*)(s_ad2 + cb + k);
        ssrc += tv.x * av.x + tv.y * av.y + tv.z * av.z + tv.w * av.w;
        sdst += tv.x * dv.x + tv.y * dv.y + tv.z * dv.z + tv.w * dv.w;
      }
      ssrc += __shfl_xor(ssrc, 1, 64); ssrc += __shfl_xor(ssrc, 2, 64);
      sdst += __shfl_xor(sdst, 1, 64); sdst += __shfl_xor(sdst, 2, 64);
      int gi = gbase + i0 + i;
      if (p == 0) { E2o[gi] = __expf(ssrc); G2o[gi] = __expf(0.2f * ssrc); }
      else if (p == 1) { F2o[gi] = (_Float16)__expf(sdst); H2o[gi] = (_Float16)__expf(0.2f * sdst); }
    }
  } else {
    // node-mean partial: column sums -> per-(block,batch) partial slot (deterministic)
    if (tid < 128) {
      float s = 0.f;
      #pragma unroll
      for (int i = 0; i < 64; i++) s += tile[i * 132 + tid];
      xmp[(((b << 4) + tile_id) << 7) + tid] = s;
    }
  }
}

// ---------------- fused MLP head (sums the 16 mean-partials) ----------------
__global__ __launch_bounds__(256) void k_head(
    const float* __restrict__ xmp, const float* __restrict__ W1, const float* __restrict__ b1,
    const float* __restrict__ W2, const float* __restrict__ b2,
    const float* __restrict__ Wpi, const float* __restrict__ bpi,
    const float* __restrict__ Wv, const float* __restrict__ bv,
    float* __restrict__ out) {
  int b = blockIdx.x, t = threadIdx.x;
  __shared__ float xs[128], h1[256], h2[128], red[4];
  if (t < 128) {
    const float* p = xmp + ((size_t)b << 11);
    float s = 0.f;
    #pragma unroll
    for (int xb = 0; xb < 16; xb++) s += p[(xb << 7) + t];
    xs[t] = s * (1.f / 1024.f);
  }
  __syncthreads();
  float s = 0.f;
  #pragma unroll 8
  for (int k = 0; k < 128; k++) s += xs[k] * W1[k * 256 + t];
  h1[t] = fmaxf(s + b1[t], 0.f);
  __syncthreads();
  if (t < 128) {
    float s2 = 0.f;
    #pragma unroll 8
    for (int k = 0; k < 256; k++) s2 += h1[k] * W2[k * 128 + t];
    h2[t] = fmaxf(s2 + b2[t], 0.f);
  }
  __syncthreads();
  float lg[4];
  #pragma unroll
  for (int q = 0; q < 4; q++) {
    int o = t + (q << 8);
    float s3 = 0.f;
    #pragma unroll 8
    for (int k = 0; k < 128; k++) s3 += h2[k] * Wpi[k * 1024 + o];
    lg[q] = s3 + bpi[o];
  }
  float mx = fmaxf(fmaxf(lg[0], lg[1]), fmaxf(lg[2], lg[3]));
  #pragma unroll
  for (int off = 32; off > 0; off >>= 1) mx = fmaxf(mx, __shfl_down(mx, off, 64));
  if ((t & 63) == 0) red[t >> 6] = mx;
  __syncthreads();
  mx = fmaxf(fmaxf(red[0], red[1]), fmaxf(red[2], red[3]));
  __syncthreads();
  float ex[4]; float sum = 0.f;
  #pragma unroll
  for (int q = 0; q < 4; q++) { ex[q] = __expf(lg[q] - mx); sum += ex[q]; }
  #pragma unroll
  for (int off = 32; off > 0; off >>= 1) sum += __shfl_down(sum, off, 64);
  if ((t & 63) == 0) red[t >> 6] = sum;
  __syncthreads();
  sum = red[0] + red[1] + red[2] + red[3];
  float rs = 1.0f / sum;
  #pragma unroll
  for (int q = 0; q < 4; q++) out[((size_t)b << 10) + t + (q << 8)] = ex[q] * rs;
  __syncthreads();
  float vp = (t < 128) ? h2[t] * Wv[t] : 0.f;
  #pragma unroll
  for (int off = 32; off > 0; off >>= 1) vp += __shfl_down(vp, off, 64);
  if ((t & 63) == 0) red[t >> 6] = vp;
  __syncthreads();
  if (t == 0) out[65536 + b] = red[0] + red[1] + red[2] + red[3] + bv[0];
}

extern "C" void kernel_launch(void* const* d_in, const int* in_sizes, int n_in,
                              void* d_out, int out_size, void* d_ws, size_t ws_size,
                              hipStream_t stream) {
  const float* nf    = (const float*)d_in[0];
  const int*   adj   = (const int*)  d_in[1];
  const float* Win   = (const float*)d_in[2];
  const float* asrc  = (const float*)d_in[3];
  const float* adst  = (const float*)d_in[4];
  const float* asrc2 = (const float*)d_in[5];
  const float* adst2 = (const float*)d_in[6];
  const float* W1    = (const float*)d_in[7];
  const float* b1    = (const float*)d_in[8];
  const float* W2    = (const float*)d_in[9];
  const float* b2    = (const float*)d_in[10];
  const float* Wpi   = (const float*)d_in[11];
  const float* bpi   = (const float*)d_in[12];
  const float* Wv    = (const float*)d_in[13];
  const float* bv    = (const float*)d_in[14];
  float* out = (float*)d_out;

  char* ws = (char*)d_ws;
  _Float16* x0 = (_Float16*)(ws);                                // 16.78 MB
  _Float16* x1 = (_Float16*)(ws + 16777216);                     // 16.78 MB
  u64* pm = (u64*)(ws + 33554432);                               // 8.39 MB
  char* S = ws + 41943040;
  float*    E1  = (float*)   (S + 2 * 262144);
  float*    G1  = (float*)   (S + 3 * 262144);
  _Float16* F1h = (_Float16*)(S + 4 * 262144);
  _Float16* H1h = (_Float16*)(S + 5 * 262144);
  float*    E2  = (float*)   (S + 8 * 262144);
  float*    G2  = (float*)   (S + 9 * 262144);
  _Float16* F2h = (_Float16*)(S + 10 * 262144);
  _Float16* H2h = (_Float16*)(S + 11 * 262144);
  float*    xmp = (float*)   (S + 12 * 262144);                  // 512 KB partials

  k_feat<<<8192, 256, 0, stream>>>(nf, Win, asrc, adst, adj, x0, pm, E1, G1, F1h, H1h);
  k_agg<1><<<1024, 256, 0, stream>>>(x0, E1, G1, F1h, H1h, pm, x1, nullptr,
                                     asrc2, adst2, E2, G2, F2h, H2h);
  k_agg<2><<<1024, 256, 0, stream>>>(x1, E2, G2, F2h, H2h, pm, nullptr, xmp,
                                     nullptr, nullptr, nullptr, nullptr, nullptr, nullptr);
  k_head<<<Bn, 256, 0, stream>>>(xmp, W1, b1, W2, b2, Wpi, bpi, Wv, bv, out);
}

// Round 9
// 498.805 us; speedup vs baseline: 1.0575x; 1.0040x over previous
//
#include <hip/hip_runtime.h>

#define Bn 64
#define Nn 1024
#define Cc 128

typedef _Float16 h8 __attribute__((ext_vector_type(8)));
typedef _Float16 h2v __attribute__((ext_vector_type(2)));
typedef float f4v __attribute__((ext_vector_type(4)));
typedef unsigned long long u64;

// ---------------- featurize + adjacency pack ----------------
// x0 = nf @ W_in (fp16 grouped layout): element (n,c) at ((n>>3)*128 + c)*8 + (n&7)
// E=exp(ai), G=exp(0.2 ai) fp32 (row side); Fh=exp(aj), Hh=exp(0.2 aj) fp16 (col side).
// alpha = mask * max(E_i*F_j, G_i*H_j) since exp(leakyrelu(e)) = max(exp(e), exp(0.2e))
// Also packs adjacency rows into bitmask pm (row-major 128 B/row).
__global__ __launch_bounds__(256) void k_feat(
    const float* __restrict__ nf, const float* __restrict__ Win,
    const float* __restrict__ asrc, const float* __restrict__ adst,
    const int* __restrict__ adj, _Float16* __restrict__ X0, u64* __restrict__ pm,
    float* __restrict__ E, float* __restrict__ G,
    _Float16* __restrict__ Fh, _Float16* __restrict__ Hh) {
  int g = blockIdx.x; int b = g >> 7; int n0 = (g & 127) << 3;
  int t = threadIdx.x; int c = t >> 1; int h = t & 1;
  int lane = t & 63, wv = t >> 6;
  __shared__ float sNf[24];
  if (t < 24) sNf[t] = nf[((size_t)(b << 10) + n0) * 3 + t];
  float w0 = Win[c], w1 = Win[Cc + c], w2 = Win[2 * Cc + c];
  float as_ = asrc[c], ad = adst[c];
  __syncthreads();
  float ps[4], pd[4];
  _Float16 hv[4];
  #pragma unroll
  for (int r = 0; r < 4; r++) {
    const float* p = sNf + ((h << 2) + r) * 3;
    float x = p[0] * w0 + p[1] * w1 + p[2] * w2;
    hv[r] = (_Float16)x; ps[r] = x * as_; pd[r] = x * ad;
  }
  *(uint2*)(X0 + ((size_t)b << 17) + ((size_t)(g & 127) << 10) + (c << 3) + (h << 2)) = *(uint2*)hv;

  // ---- adjacency bit-pack: wave wv packs rows n0+2*wv, n0+2*wv+1 of batch b ----
  {
    ushort* pmu = (ushort*)pm;
    int row = n0 + (wv << 1);
    const uint4* ar = (const uint4*)(adj + (((size_t)(b << 10) + row) << 10));
    #pragma unroll
    for (int rr = 0; rr < 2; rr++) {
      uint4 v0 = ar[(lane << 2) | 0], v1 = ar[(lane << 2) | 1];
      uint4 v2 = ar[(lane << 2) | 2], v3 = ar[(lane << 2) | 3];
      unsigned int bits =
          (v0.x) | (v0.y << 1) | (v0.z << 2) | (v0.w << 3) |
          (v1.x << 4) | (v1.y << 5) | (v1.z << 6) | (v1.w << 7) |
          (v2.x << 8) | (v2.y << 9) | (v2.z << 10) | (v2.w << 11) |
          (v3.x << 12) | (v3.y << 13) | (v3.z << 14) | (v3.w << 15);
      pmu[(((size_t)(b << 10) + row + rr) << 6) + lane] = (ushort)bits;
      ar += 256;  // next row (1024 ints)
    }
  }

  #pragma unroll
  for (int off = 32; off > 1; off >>= 1) {
    #pragma unroll
    for (int r = 0; r < 4; r++) { ps[r] += __shfl_down(ps[r], off, 64); pd[r] += __shfl_down(pd[r], off, 64); }
  }
  __shared__ float red[4][2][4][2];
  if (lane < 2) {
    #pragma unroll
    for (int r = 0; r < 4; r++) { red[wv][lane][r][0] = ps[r]; red[wv][lane][r][1] = pd[r]; }
  }
  __syncthreads();
  if (t < 8) {
    int hh = t >> 2, r = t & 3;
    float sa = 0.f, sd = 0.f;
    #pragma unroll
    for (int w = 0; w < 4; w++) { sa += red[w][hh][r][0]; sd += red[w][hh][r][1]; }
    int gi = (b << 10) + n0 + t;
    E[gi] = __expf(sa); G[gi] = __expf(0.2f * sa);
    Fh[gi] = (_Float16)__expf(sd); Hh[gi] = (_Float16)__expf(0.2f * sd);
  }
}

// ------- MFMA aggregation: 64-row tiles, deep-pipelined K-loop -------
// out[i,c] = relu( (1/den_i) * sum_j alpha_ij * x[j,c] ),  den_i = sum_j alpha_ij
// alpha_ij = mask_ij * max(E_i*F_j, G_i*H_j)
// r2 profile: VALUBusy 23%, MfmaUtil 4% -> neither pipe saturated => EXPOSED LATENCY.
// r6 (occupancy) and r8 (VALU cut) both ~null. This round pipelines ALL per-kt inputs:
//   * global B fragments: 2-deep prefetch (covers ~200cy L2 latency)
//   * LDS F/H uint4 + mask bytes: 1-deep prefetch (covers ~120cy LDS latency)
// via a 4-buffer rotation, unroll-4, all-static register indexing.
// s_setprio(1) around the MFMA cluster (waves are barrier-free/phase-diverse here).
// B straight from global (grouped layout == fragment layout, XCD-pinned: lin&63=batch).
// den via accD = mfma(A, ones): reg r of lane (m,quad) = den[row quad*4+r] (exact C rows).
// Tail prefetches (GL<=33, LL<=32) land in valid ws/LDS memory (benign).
template <int LAYER>
__global__ __launch_bounds__(256, 3) void k_agg(
    const _Float16* __restrict__ X,
    const float* __restrict__ E, const float* __restrict__ G,
    const _Float16* __restrict__ Fh, const _Float16* __restrict__ Hh,
    const u64* __restrict__ pm, _Float16* __restrict__ Y, float* __restrict__ xmp,
    const float* __restrict__ as2, const float* __restrict__ ad2,
    float* __restrict__ E2o, float* __restrict__ G2o,
    _Float16* __restrict__ F2o, _Float16* __restrict__ H2o) {
  __shared__ __align__(16) char smem[34816];
  _Float16* s_Fh = (_Float16*)smem;                      // 2 KB (1024 fp16)
  _Float16* s_Hh = (_Float16*)(smem + 2048);             // 2 KB
  unsigned char* s_pm = (unsigned char*)(smem + 4096);   // 64 rows x 152 B = 9728 B
  float* tile = (float*)smem;                            // epilogue overlay [64][132] = 33792 B
  float* s_as2 = (float*)(smem + 33792);                 // 512 B (LAYER 1 only)
  float* s_ad2 = (float*)(smem + 34304);                 // 512 B

  // XCD-locality swizzle: batch = lin & 63 -> batch b's 16 tiles on XCD (b % 8)
  const int lin = blockIdx.x;
  const int b = lin & 63, tile_id = lin >> 6, i0 = tile_id << 6;
  const int tid = threadIdx.x;
  const int lane = tid & 63, wv = tid >> 6;
  const int m = lane & 15, quad = lane >> 4;
  const int wi = wv >> 1, wc = wv & 1;
  const int gbase = b << 10;

  // stage col-side packed fp16 arrays (Fh, Hh) and packed mask
  ((uint2*)s_Fh)[tid] = ((const uint2*)(Fh + gbase))[tid];
  ((uint2*)s_Hh)[tid] = ((const uint2*)(Hh + gbase))[tid];
  {
    const u64* pmg = pm + ((size_t)(gbase + i0) << 4);
    #pragma unroll
    for (int k = tid; k < 1024; k += 256) {
      int r = k >> 4, w = k & 15;
      *(u64*)(s_pm + r * 152 + (w << 3)) = pmg[k];
    }
  }
  if (LAYER == 1 && tid < 128) { s_as2[tid] = as2[tid]; s_ad2[tid] = ad2[tid]; }

  // per-lane row constants: this lane owns output rows r0 = wi*32+m and r0+16
  const int r0 = (wi << 5) + m;
  const int gi0 = gbase + i0 + r0;
  const _Float16 e0 = (_Float16)E[gi0],      g0 = (_Float16)G[gi0];
  const _Float16 e1 = (_Float16)E[gi0 + 16], g1 = (_Float16)G[gi0 + 16];
  const h2v E0p = {e0, e0}, G0p = {g0, g0}, E1p = {e1, e1}, G1p = {g1, g1};

  f4v acc[2][4];
  #pragma unroll
  for (int a = 0; a < 2; a++)
    #pragma unroll
    for (int ct = 0; ct < 4; ct++) { f4v z = {0.f, 0.f, 0.f, 0.f}; acc[a][ct] = z; }
  f4v accD0 = {0.f, 0.f, 0.f, 0.f}, accD1 = {0.f, 0.f, 0.f, 0.f};
  const h8 kOne = {(_Float16)1.f, (_Float16)1.f, (_Float16)1.f, (_Float16)1.f,
                   (_Float16)1.f, (_Float16)1.f, (_Float16)1.f, (_Float16)1.f};

  // B fragment base: grouped layout => global byte offset == fragment byte offset
  const char* gB = (const char*)(X + ((size_t)b << 17)) + (((quad << 7) + (wc << 6) + m) << 4);
  const unsigned char* pmr0 = s_pm + r0 * 152;
  const unsigned char* pmr1 = pmr0 + 16 * 152;

  __syncthreads();  // staging visible to all waves

  // bit-mask byte -> 4 u32 AND-masks (fp16x2 lanes)
  auto expand = [](unsigned mb, unsigned M[4]) {
    unsigned slo = ((mb & 0xFu) * 0x204081u) & 0x01010101u;
    unsigned shi = (((mb >> 4) & 0xFu) * 0x204081u) & 0x01010101u;
    slo *= 0xFFu; shi *= 0xFFu;
    M[0] = __builtin_amdgcn_perm(slo, slo, 0x01010000u);
    M[1] = __builtin_amdgcn_perm(slo, slo, 0x03030202u);
    M[2] = __builtin_amdgcn_perm(shi, shi, 0x01010000u);
    M[3] = __builtin_amdgcn_perm(shi, shi, 0x03030202u);
  };

  // GL: global B fragments (2-deep). LL: LDS F/H pairs + mask bytes (1-deep).
  auto GL = [&](int kt, h8* Bf) {
    const char* gp = gB + ((size_t)kt << 13);
    Bf[0] = *(const h8*)gp;          Bf[1] = *(const h8*)(gp + 256);
    Bf[2] = *(const h8*)(gp + 512);  Bf[3] = *(const h8*)(gp + 768);
  };
  auto LL = [&](int kt, uint4& Fp, uint4& Hp, unsigned& mb0, unsigned& mb1) {
    const int j0 = (kt << 5) + (quad << 3);
    Fp = *(const uint4*)((const char*)s_Fh + (j0 << 1));
    Hp = *(const uint4*)((const char*)s_Hh + (j0 << 1));
    mb0 = pmr0[(kt << 2) + quad];    mb1 = pmr1[(kt << 2) + quad];
  };
  auto COMP = [&](const h8* Bf, uint4 Fp, uint4 Hp, unsigned mb0, unsigned mb1) {
    unsigned M0[4], M1[4];
    expand(mb0, M0); expand(mb1, M1);
    union { h8 v; unsigned u[4]; } A0, A1;
    const unsigned* fu = (const unsigned*)&Fp;
    const unsigned* hu = (const unsigned*)&Hp;
    #pragma unroll
    for (int q = 0; q < 4; q++) {
      h2v f2, h2;
      __builtin_memcpy(&f2, &fu[q], 4); __builtin_memcpy(&h2, &hu[q], 4);
      h2v mx0 = __builtin_elementwise_max(E0p * f2, G0p * h2);  // v_pk_mul + v_pk_max
      h2v mx1 = __builtin_elementwise_max(E1p * f2, G1p * h2);
      unsigned m0u, m1u;
      __builtin_memcpy(&m0u, &mx0, 4); __builtin_memcpy(&m1u, &mx1, 4);
      A0.u[q] = m0u & M0[q];
      A1.u[q] = m1u & M1[q];
    }
    __builtin_amdgcn_s_setprio(1);
    acc[0][0] = __builtin_amdgcn_mfma_f32_16x16x32_f16(A0.v, Bf[0], acc[0][0], 0, 0, 0);
    acc[1][0] = __builtin_amdgcn_mfma_f32_16x16x32_f16(A1.v, Bf[0], acc[1][0], 0, 0, 0);
    acc[0][1] = __builtin_amdgcn_mfma_f32_16x16x32_f16(A0.v, Bf[1], acc[0][1], 0, 0, 0);
    acc[1][1] = __builtin_amdgcn_mfma_f32_16x16x32_f16(A1.v, Bf[1], acc[1][1], 0, 0, 0);
    acc[0][2] = __builtin_amdgcn_mfma_f32_16x16x32_f16(A0.v, Bf[2], acc[0][2], 0, 0, 0);
    acc[1][2] = __builtin_amdgcn_mfma_f32_16x16x32_f16(A1.v, Bf[2], acc[1][2], 0, 0, 0);
    acc[0][3] = __builtin_amdgcn_mfma_f32_16x16x32_f16(A0.v, Bf[3], acc[0][3], 0, 0, 0);
    acc[1][3] = __builtin_amdgcn_mfma_f32_16x16x32_f16(A1.v, Bf[3], acc[1][3], 0, 0, 0);
    accD0 = __builtin_amdgcn_mfma_f32_16x16x32_f16(A0.v, kOne, accD0, 0, 0, 0);
    accD1 = __builtin_amdgcn_mfma_f32_16x16x32_f16(A1.v, kOne, accD1, 0, 0, 0);
    __builtin_amdgcn_s_setprio(0);
  };

  // 4-buffer B rotation (2-deep) + 2-buffer L rotation (1-deep), unroll-4
  h8 B0[4], B1[4], B2[4], B3[4];
  uint4 Fp0, Hp0, Fp1, Hp1;
  unsigned ma0, mb0_, ma1, mb1_;
  GL(0, B0); GL(1, B1); LL(0, Fp0, Hp0, ma0, mb0_);
  for (int kt = 0; kt < 32; kt += 4) {
    GL(kt + 2, B2); LL(kt + 1, Fp1, Hp1, ma1, mb1_); COMP(B0, Fp0, Hp0, ma0, mb0_);
    GL(kt + 3, B3); LL(kt + 2, Fp0, Hp0, ma0, mb0_); COMP(B1, Fp1, Hp1, ma1, mb1_);
    GL(kt + 4, B0); LL(kt + 3, Fp1, Hp1, ma1, mb1_); COMP(B2, Fp0, Hp0, ma0, mb0_);
    GL(kt + 5, B1); LL(kt + 4, Fp0, Hp0, ma0, mb0_); COMP(B3, Fp1, Hp1, ma1, mb1_);
  }

  // per-lane reciprocal denominators: reg r of accD{a} = den[row (wi*32 + a*16 + quad*4 + r)]
  float rd8[2][4];
  #pragma unroll
  for (int r = 0; r < 4; r++) { rd8[0][r] = 1.0f / accD0[r]; rd8[1][r] = 1.0f / accD1[r]; }

  __syncthreads();  // all waves done reading s_Fh/s_Hh/s_pm before tile overlay
  // write relu(acc/den) into fp32 tile [64][132]
  #pragma unroll
  for (int a = 0; a < 2; a++)
    #pragma unroll
    for (int ct = 0; ct < 4; ct++)
      #pragma unroll
      for (int r = 0; r < 4; r++) {
        int lr = (wi << 5) + (a << 4) + (quad << 2) + r;
        int c = (wc << 6) + (ct << 4) + m;
        tile[lr * 132 + c] = fmaxf(acc[a][ct][r] * rd8[a][r], 0.f);
      }
  __syncthreads();
  if (LAYER == 1) {
    // coalesced fp16 grouped-layout store: block region is contiguous [i0*128, +8192)
    _Float16 hv[32];
    #pragma unroll
    for (int s = 0; s < 32; s++) {
      int q = (tid << 5) + s;
      int li = ((q >> 10) << 3) + (q & 7), c = (q >> 3) & 127;
      hv[s] = (_Float16)tile[li * 132 + c];
    }
    uint4* o = (uint4*)(Y + ((size_t)b << 17) + ((size_t)i0 << 7) + (tid << 5));
    o[0] = *(uint4*)&hv[0]; o[1] = *(uint4*)&hv[8];
    o[2] = *(uint4*)&hv[16]; o[3] = *(uint4*)&hv[24];
    // fused layer-2 scores: row i of this tile, from fp32 values.
    {
      int i = tid >> 2, p = tid & 3, cb = p << 5;
      const float* trow = tile + i * 132 + cb;
      float ssrc = 0.f, sdst = 0.f;
      #pragma unroll
      for (int k = 0; k < 32; k += 4) {
        float4 tv = *(const float4*)(trow + k);
        float4 av = *(const float4*)(s_as2 + cb + k);
        float4 dv = *(const float4*)(s_ad2 + cb + k);
        ssrc += tv.x * av.x + tv.y * av.y + tv.z * av.z + tv.w * av.w;
        sdst += tv.x * dv.x + tv.y * dv.y + tv.z * dv.z + tv.w * dv.w;
      }
      ssrc += __shfl_xor(ssrc, 1, 64); ssrc += __shfl_xor(ssrc, 2, 64);
      sdst += __shfl_xor(sdst, 1, 64); sdst += __shfl_xor(sdst, 2, 64);
      int gi = gbase + i0 + i;
      if (p == 0) { E2o[gi] = __expf(ssrc); G2o[gi] = __expf(0.2f * ssrc); }
      else if (p == 1) { F2o[gi] = (_Float16)__expf(sdst); H2o[gi] = (_Float16)__expf(0.2f * sdst); }
    }
  } else {
    // node-mean partial: column sums -> per-(block,batch) partial slot (deterministic)
    if (tid < 128) {
      float s = 0.f;
      #pragma unroll
      for (int i = 0; i < 64; i++) s += tile[i * 132 + tid];
      xmp[(((b << 4) + tile_id) << 7) + tid] = s;
    }
  }
}

// ---------------- fused MLP head (sums the 16 mean-partials) ----------------
__global__ __launch_bounds__(256) void k_head(
    const float* __restrict__ xmp, const float* __restrict__ W1, const float* __restrict__ b1,
    const float* __restrict__ W2, const float* __restrict__ b2,
    const float* __restrict__ Wpi, const float* __restrict__ bpi,
    const float* __restrict__ Wv, const float* __restrict__ bv,
    float* __restrict__ out) {
  int b = blockIdx.x, t = threadIdx.x;
  __shared__ float xs[128], h1[256], h2[128], red[4];
  if (t < 128) {
    const float* p = xmp + ((size_t)b << 11);
    float s = 0.f;
    #pragma unroll
    for (int xb = 0; xb < 16; xb++) s += p[(xb << 7) + t];
    xs[t] = s * (1.f / 1024.f);
  }
  __syncthreads();
  float s = 0.f;
  #pragma unroll 8
  for (int k = 0; k < 128; k++) s += xs[k] * W1[k * 256 + t];
  h1[t] = fmaxf(s + b1[t], 0.f);
  __syncthreads();
  if (t < 128) {
    float s2 = 0.f;
    #pragma unroll 8
    for (int k = 0; k < 256; k++) s2 += h1[k] * W2[k * 128 + t];
    h2[t] = fmaxf(s2 + b2[t], 0.f);
  }
  __syncthreads();
  float lg[4];
  #pragma unroll
  for (int q = 0; q < 4; q++) {
    int o = t + (q << 8);
    float s3 = 0.f;
    #pragma unroll 8
    for (int k = 0; k < 128; k++) s3 += h2[k] * Wpi[k * 1024 + o];
    lg[q] = s3 + bpi[o];
  }
  float mx = fmaxf(fmaxf(lg[0], lg[1]), fmaxf(lg[2], lg[3]));
  #pragma unroll
  for (int off = 32; off > 0; off >>= 1) mx = fmaxf(mx, __shfl_down(mx, off, 64));
  if ((t & 63) == 0) red[t >> 6] = mx;
  __syncthreads();
  mx = fmaxf(fmaxf(red[0], red[1]), fmaxf(red[2], red[3]));
  __syncthreads();
  float ex[4]; float sum = 0.f;
  #pragma unroll
  for (int q = 0; q < 4; q++) { ex[q] = __expf(lg[q] - mx); sum += ex[q]; }
  #pragma unroll
  for (int off = 32; off > 0; off >>= 1) sum += __shfl_down(sum, off, 64);
  if ((t & 63) == 0) red[t >> 6] = sum;
  __syncthreads();
  sum = red[0] + red[1] + red[2] + red[3];
  float rs = 1.0f / sum;
  #pragma unroll
  for (int q = 0; q < 4; q++) out[((size_t)b << 10) + t + (q << 8)] = ex[q] * rs;
  __syncthreads();
  float vp = (t < 128) ? h2[t] * Wv[t] : 0.f;
  #pragma unroll
  for (int off = 32; off > 0; off >>= 1) vp += __shfl_down(vp, off, 64);
  if ((t & 63) == 0) red[t >> 6] = vp;
  __syncthreads();
  if (t == 0) out[65536 + b] = red[0] + red[1] + red[2] + red[3] + bv[0];
}

extern "C" void kernel_launch(void* const* d_in, const int* in_sizes, int n_in,
                              void* d_out, int out_size, void* d_ws, size_t ws_size,
                              hipStream_t stream) {
  const float* nf    = (const float*)d_in[0];
  const int*   adj   = (const int*)  d_in[1];
  const float* Win   = (const float*)d_in[2];
  const float* asrc  = (const float*)d_in[3];
  const float* adst  = (const float*)d_in[4];
  const float* asrc2 = (const float*)d_in[5];
  const float* adst2 = (const float*)d_in[6];
  const float* W1    = (const float*)d_in[7];
  const float* b1    = (const float*)d_in[8];
  const float* W2    = (const float*)d_in[9];
  const float* b2    = (const float*)d_in[10];
  const float* Wpi   = (const float*)d_in[11];
  const float* bpi   = (const float*)d_in[12];
  const float* Wv    = (const float*)d_in[13];
  const float* bv    = (const float*)d_in[14];
  float* out = (float*)d_out;

  char* ws = (char*)d_ws;
  _Float16* x0 = (_Float16*)(ws);                                // 16.78 MB
  _Float16* x1 = (_Float16*)(ws + 16777216);                     // 16.78 MB
  u64* pm = (u64*)(ws + 33554432);                               // 8.39 MB
  char* S = ws + 41943040;
  float*    E1  = (float*)   (S + 2 * 262144);
  float*    G1  = (float*)   (S + 3 * 262144);
  _Float16* F1h = (_Float16*)(S + 4 * 262144);
  _Float16* H1h = (_Float16*)(S + 5 * 262144);
  float*    E2  = (float*)   (S + 8 * 262144);
  float*    G2  = (float*)   (S + 9 * 262144);
  _Float16* F2h = (_Float16*)(S + 10 * 262144);
  _Float16* H2h = (_Float16*)(S + 11 * 262144);
  float*    xmp = (float*)   (S + 12 * 262144);                  // 512 KB partials

  k_feat<<<8192, 256, 0, stream>>>(nf, Win, asrc, adst, adj, x0, pm, E1, G1, F1h, H1h);
  k_agg<1><<<1024, 256, 0, stream>>>(x0, E1, G1, F1h, H1h, pm, x1, nullptr,
                                     asrc2, adst2, E2, G2, F2h, H2h);
  k_agg<2><<<1024, 256, 0, stream>>>(x1, E2, G2, F2h, H2h, pm, nullptr, xmp,
                                     nullptr, nullptr, nullptr, nullptr, nullptr, nullptr);
  k_head<<<Bn, 256, 0, stream>>>(xmp, W1, b1, W2, b2, Wpi, bpi, Wv, bv, out);
}